// Round 13
// baseline (650.683 us; speedup 1.0000x reference)
//
#include <hip/hip_runtime.h>

#define HDIM 128
#define SEQ  14
#define G4   512
#define TLEN 8
#define NTHR 512
#define HPITCH 160   // halves per elem row (320 B): bank-colored

typedef _Float16 half8 __attribute__((ext_vector_type(8)));
typedef float f32x4 __attribute__((ext_vector_type(4)));
typedef float f32x2 __attribute__((ext_vector_type(2)));
typedef int   i32x4 __attribute__((ext_vector_type(4)));

#define LOG2E  1.44269504f
#define LOG2E2 2.88539008f

__device__ __forceinline__ float frcp_(float x) { return __builtin_amdgcn_rcpf(x); }
#if defined(__has_builtin)
#if __has_builtin(__builtin_amdgcn_exp2f)
#define EXP2_(x) __builtin_amdgcn_exp2f(x)
#endif
#endif
#ifndef EXP2_
#define EXP2_(x) __expf((x) * 0.69314718f)
#endif
// inputs pre-scaled by log2e (sig) / 2*log2e (tanh):
__device__ __forceinline__ float fsigP_(float y)  { return frcp_(1.0f + EXP2_(-y)); }
__device__ __forceinline__ float ftanhP_(float y) { return 1.0f - 2.0f * frcp_(EXP2_(y) + 1.0f); }
// unscaled (scores path):
__device__ __forceinline__ float ftanh_(float x)  { return ftanhP_(x * LOG2E2); }

// Broadcast in-quad lane J's 16B (half8) to all 4 lanes of each DPP quad.
template<int CTRL>
__device__ __forceinline__ half8 qbcast_(half8 v) {
    i32x4 iv = __builtin_bit_cast(i32x4, v);
    i32x4 r;
    r[0] = __builtin_amdgcn_mov_dpp(iv[0], CTRL, 0xF, 0xF, true);
    r[1] = __builtin_amdgcn_mov_dpp(iv[1], CTRL, 0xF, 0xF, true);
    r[2] = __builtin_amdgcn_mov_dpp(iv[2], CTRL, 0xF, 0xF, true);
    r[3] = __builtin_amdgcn_mov_dpp(iv[3], CTRL, 0xF, 0xF, true);
    return __builtin_bit_cast(half8, r);
}

// Load all 4 A-fragments with ONE ds_read_b128 per lane: lane l&3=j reads
// kt-chunk j (all 64 lanes distinct -> 512B fully utilized, banks 4-deep
// balanced), then DPP quad_perm broadcasts reconstruct kt0..kt3 per lane.
__device__ __forceinline__ void load_afrags_(
    const _Float16* __restrict__ base, int q, int l, half8 (&a)[4])
{
    const _Float16* sp = base + ((l >> 2) & 1) * HPITCH + 8 * q + 32 * (l & 3);
    half8 mine = *(const half8*)(sp);
    a[0] = qbcast_<0x00>(mine);
    a[1] = qbcast_<0x55>(mine);
    a[2] = qbcast_<0xAA>(mine);
    a[3] = qbcast_<0xFF>(mine);
}

struct __align__(16) SMem {
    __align__(16) float zq[4];             // persistent zero quad (opaque to compiler)
    _Float16 h2[2][2][HPITCH];             // [buf][elem][col], bank-colored
    _Float16 ench[SEQ][2][HPITCH];         // encoder outputs, bank-colored
    _Float16 encWe[SEQ][2][HDIM];          // enc_out @ We
    _Float16 hWdh[2][HDIM];                // h @ Wd
    __align__(16) float ctx2[HDIM + 1][2]; // [s][e]; row 128 = x
    __align__(16) float inp2[SEQ][2];
    float attnw[2][SEQ];
    float asum[2][SEQ];
    float score[2][SEQ];
    float wv[HDIM];
    float wf[HDIM];
};

// One LSTM step for 2 batch elements. A-row r carries elem (r>>2)&1, so for
// writer lanes q<2, D reg0 (= row 4q) is the lane's own element's gate value.
// Weights pre-scaled by log2e (i,f,o) / 2*log2e (g) for bare v_exp_f32.
// Caller must __syncthreads() after.
__device__ __forceinline__ float lstm_core(
    const _Float16* __restrict__ srcBase,  // &h2[buf][0][0]
    _Float16* __restrict__ dstw,           // &h2[nxt][q][16w+l] (q<2)
    f32x2 xv, f32x4 zeroq,
    const half8 (&whh)[4][4], const float (&wih)[4], const float (&bia)[4],
    float& c, int q, int l)
{
    half8 a[4];
    load_afrags_(srcBase, q, l, a);
    f32x4 A[4];
    #pragma unroll
    for (int g = 0; g < 4; ++g) {
        A[g] = __builtin_amdgcn_mfma_f32_16x16x32_f16(a[0], whh[g][0], zeroq, 0, 0, 0);
        A[g] = __builtin_amdgcn_mfma_f32_16x16x32_f16(a[1], whh[g][1], A[g], 0, 0, 0);
        A[g] = __builtin_amdgcn_mfma_f32_16x16x32_f16(a[2], whh[g][2], A[g], 0, 0, 0);
        A[g] = __builtin_amdgcn_mfma_f32_16x16x32_f16(a[3], whh[g][3], A[g], 0, 0, 0);
    }
    float hn = 0.0f;
    if (q < 2) {                           // writer lanes; reg0 = own element
        float x = (q & 1) ? xv[1] : xv[0];
        float ig = fsigP_(fmaf(x, wih[0], bia[0]) + A[0][0]);
        float fg = fsigP_(fmaf(x, wih[1], bia[1]) + A[1][0]);
        float gg = ftanhP_(fmaf(x, wih[2], bia[2]) + A[2][0]);
        float og = fsigP_(fmaf(x, wih[3], bia[3]) + A[3][0]);
        c = fmaf(fg, c, ig * gg);
        hn = og * ftanhP_(c * LOG2E2);
        *dstw = (_Float16)hn;
    }
    return hn;
}

__global__ __launch_bounds__(NTHR, 2) void seq2seq_kernel(
    const float* __restrict__ inputs,
    const float* __restrict__ Wih_e, const float* __restrict__ Whh_e, const float* __restrict__ b_e,
    const float* __restrict__ Wih_d, const float* __restrict__ Whh_d, const float* __restrict__ b_d,
    const float* __restrict__ We, const float* __restrict__ Wd,
    const float* __restrict__ Wv, const float* __restrict__ Wf, const float* __restrict__ bfp,
    float* __restrict__ out, int B)
{
    const int tid  = threadIdx.x;
    const int b0   = blockIdx.x * 2;
    const int w    = tid >> 6;
    const int lane = tid & 63;
    const int q    = lane >> 4;
    const int l    = lane & 15;
    const int wrcol = 16 * w + l;
    __shared__ SMem S;

    const _Float16* s0 = &S.h2[0][0][0];
    const _Float16* s1 = &S.h2[1][0][0];
    _Float16* d0 = &S.h2[0][q & 1][wrcol];
    _Float16* d1 = &S.h2[1][q & 1][wrcol];

    // gate scales: i,f,o -> log2e ; g -> 2*log2e
    const float gscale[4] = {LOG2E, LOG2E, LOG2E2, LOG2E};

    // ---- init ----
    if (tid < 4) S.zq[tid] = 0.0f;
    if (tid < 2 * HDIM) {
        int e = tid >> 7, j = tid & 127;
        S.h2[0][e][j] = (_Float16)0.0f;
        S.h2[1][e][j] = (_Float16)0.0f;
    }
    if (tid < SEQ * 2) {
        int t = tid >> 1, m = tid & 1;
        S.inp2[t][m] = inputs[(b0 + m) * SEQ + t];
        S.asum[m][t] = 0.0f;
    }
    if (tid < HDIM) { S.wv[tid] = Wv[tid]; S.wf[tid] = Wf[tid]; }
    if (tid < 2) S.ctx2[HDIM][tid] = inputs[(b0 + tid) * SEQ + (SEQ - 1)];

    // ---- encoder weights (B-frags, pre-scaled) ----
    half8 whh[4][4];
    float wih[4], bia[4];
    #pragma unroll
    for (int g = 0; g < 4; ++g) {
        int n = g * HDIM + wrcol;
        float sc = gscale[g];
        wih[g] = Wih_e[n] * sc;
        bia[g] = b_e[n] * sc;
        #pragma unroll
        for (int kt = 0; kt < 4; ++kt) {
            half8 f;
            #pragma unroll
            for (int jj = 0; jj < 8; ++jj)
                f[jj] = (_Float16)(Whh_e[(32 * kt + 8 * q + jj) * G4 + n] * sc);
            whh[g][kt] = f;
        }
    }
    float c = 0.0f;
    __syncthreads();

    const f32x4 zeroq = *(const f32x4*)S.zq;   // opaque zeros: 4 persistent VGPRs

    // ---- encoder: 14 steps (7 static-parity pairs), x prefetched across barrier ----
    f32x2 xv = *(const f32x2*)&S.inp2[0][0];
    for (int t = 0; t < SEQ; t += 2) {
        float hn = lstm_core(s0, d1, xv, zeroq, whh, wih, bia, c, q, l);
        if (q < 2) S.ench[t][q][wrcol] = (_Float16)hn;
        xv = *(const f32x2*)&S.inp2[t + 1][0];
        __syncthreads();
        hn = lstm_core(s1, d0, xv, zeroq, whh, wih, bia, c, q, l);
        if (q < 2) S.ench[t + 1][q][wrcol] = (_Float16)hn;
        if (t + 2 < SEQ) xv = *(const f32x2*)&S.inp2[t + 2][0];
        __syncthreads();
    }
    // h now in h2[0]

    // ---- encWe = enc_out @ We (one-time; unscaled weights) ----
    {
        half8 wef[4];
        #pragma unroll
        for (int kt = 0; kt < 4; ++kt) {
            half8 f;
            #pragma unroll
            for (int jj = 0; jj < 8; ++jj)
                f[jj] = (_Float16)We[(32 * kt + 8 * q + jj) * HDIM + wrcol];
            wef[kt] = f;
        }
        for (int t = 0; t < SEQ; ++t) {
            half8 a[4];
            load_afrags_(&S.ench[t][0][0], q, l, a);
            f32x4 dv = zeroq;
            #pragma unroll
            for (int kt = 0; kt < 4; ++kt)
                dv = __builtin_amdgcn_mfma_f32_16x16x32_f16(a[kt], wef[kt], dv, 0, 0, 0);
            if (q < 2) S.encWe[t][q][wrcol] = (_Float16)dv[0];  // reg0 = row 4q = elem q
        }
    }

    // ---- decoder weights (pre-scaled) ----
    half8 wdf[4];
    #pragma unroll
    for (int g = 0; g < 4; ++g) {
        int n = g * HDIM + wrcol;
        float sc = gscale[g];
        wih[g] = Wih_d[n] * sc;
        bia[g] = b_d[n] * sc;
        #pragma unroll
        for (int kt = 0; kt < 4; ++kt) {
            half8 f;
            #pragma unroll
            for (int jj = 0; jj < 8; ++jj)
                f[jj] = (_Float16)(Whh_d[(32 * kt + 8 * q + jj) * G4 + n] * sc);
            whh[g][kt] = f;
        }
    }
    #pragma unroll
    for (int kt = 0; kt < 4; ++kt) {
        half8 f;
        #pragma unroll
        for (int jj = 0; jj < 8; ++jj)
            f[jj] = (_Float16)Wd[(32 * kt + 8 * q + jj) * HDIM + wrcol];
        wdf[kt] = f;
    }
    float bf0 = bfp[0];
    __syncthreads();   // encWe + x0 visible

    // ---- decoder: 8 steps, parity alternates (h enters in h2[0]) ----
    #pragma unroll 1
    for (int dd = 0; dd < TLEN; ++dd) {
        const bool even = (dd & 1) == 0;
        const _Float16* sC = even ? s0 : s1;
        const _Float16* sO = even ? s1 : s0;
        _Float16* dC = even ? d0 : d1;
        _Float16* dO = even ? d1 : d0;

        // hWd = h @ Wd
        {
            half8 a[4];
            load_afrags_(sC, q, l, a);
            f32x4 dv = zeroq;
            #pragma unroll
            for (int kt = 0; kt < 4; ++kt)
                dv = __builtin_amdgcn_mfma_f32_16x16x32_f16(a[kt], wdf[kt], dv, 0, 0, 0);
            if (q < 2) S.hWdh[q][wrcol] = (_Float16)dv[0];
        }
        __syncthreads();
        // scores
        if (tid < 2 * SEQ * 16) {
            int p = tid >> 4, sub = tid & 15;
            int m = p & 1, t = p >> 1;
            float s = 0.0f;
            #pragma unroll
            for (int i = 0; i < 8; ++i) {
                int j = sub * 8 + i;
                s = fmaf(ftanh_((float)S.encWe[t][m][j] + (float)S.hWdh[m][j]), S.wv[j], s);
            }
            s += __shfl_down(s, 8, 16);
            s += __shfl_down(s, 4, 16);
            s += __shfl_down(s, 2, 16);
            s += __shfl_down(s, 1, 16);
            if (sub == 0) S.score[m][t] = s;
        }
        __syncthreads();
        // softmax over 14 per element
        if (tid < 2) {
            int m = tid;
            float sc[SEQ]; float mx = -1e30f;
            #pragma unroll
            for (int t = 0; t < SEQ; ++t) { sc[t] = S.score[m][t]; mx = fmaxf(mx, sc[t]); }
            float ssum = 0.0f;
            #pragma unroll
            for (int t = 0; t < SEQ; ++t) { float e = __expf(sc[t] - mx); sc[t] = e; ssum += e; }
            float inv = frcp_(ssum);
            #pragma unroll
            for (int t = 0; t < SEQ; ++t) {
                float a = sc[t] * inv;
                S.attnw[m][t] = a;
                S.asum[m][t] += a;
            }
        }
        __syncthreads();
        // context -> ctx2[j][e]
        if (tid < 256) {
            int e = tid >> 7, j = tid & 127;
            float a = 0.0f;
            #pragma unroll
            for (int t = 0; t < SEQ; ++t)
                a = fmaf(S.attnw[e][t], (float)S.ench[t][e][j], a);
            S.ctx2[j][e] = a;
        }
        __syncthreads();

        // decoder LSTM: 129 steps = 64 static-parity pairs + 1; x prefetched
        const f32x2* xp = (const f32x2*)&S.ctx2[0][0];
        f32x2 xd = xp[0];
        #pragma unroll 1
        for (int s2 = 0; s2 < 64; ++s2) {
            (void)lstm_core(sC, dO, xd, zeroq, whh, wih, bia, c, q, l);
            xd = xp[2 * s2 + 1];           // issued before the barrier
            __syncthreads();
            (void)lstm_core(sO, dC, xd, zeroq, whh, wih, bia, c, q, l);
            xd = xp[2 * s2 + 2];           // s2=63 -> xp[128] = x row, valid
            __syncthreads();
        }
        (void)lstm_core(sC, dO, xd, zeroq, whh, wih, bia, c, q, l);
        __syncthreads();
        // h now in the "other" buffer; output projection -> next x
        const _Float16* hO = even ? &S.h2[1][0][0] : &S.h2[0][0][0];
        if (tid < 32) {
            int m = tid >> 4, part = tid & 15;
            half8 hv = *(const half8*)(hO + m * HPITCH + part * 8);
            float s = 0.0f;
            #pragma unroll
            for (int i = 0; i < 8; ++i) s = fmaf((float)hv[i], S.wf[part * 8 + i], s);
            s += __shfl_down(s, 8, 16);
            s += __shfl_down(s, 4, 16);
            s += __shfl_down(s, 2, 16);
            s += __shfl_down(s, 1, 16);
            if (part == 0) {
                float o = s + bf0;
                out[(b0 + m) * TLEN + dd] = o;
                S.ctx2[HDIM][m] = o;
            }
        }
        __syncthreads();
    }

    // total_attn [B, 14, 1]
    if (tid < 2 * SEQ) {
        int m = tid / SEQ, t = tid % SEQ;
        out[B * TLEN + (b0 + m) * SEQ + t] = S.asum[m][t];
    }
}

extern "C" void kernel_launch(void* const* d_in, const int* in_sizes, int n_in,
                              void* d_out, int out_size, void* d_ws, size_t ws_size,
                              hipStream_t stream) {
    const float* inputs = (const float*)d_in[0];
    const float* Wih_e = (const float*)d_in[2];
    const float* Whh_e = (const float*)d_in[3];
    const float* b_e   = (const float*)d_in[4];
    const float* Wih_d = (const float*)d_in[5];
    const float* Whh_d = (const float*)d_in[6];
    const float* b_d   = (const float*)d_in[7];
    const float* We    = (const float*)d_in[8];
    const float* Wd    = (const float*)d_in[9];
    const float* Wv    = (const float*)d_in[10];
    const float* Wf    = (const float*)d_in[11];
    const float* bfp   = (const float*)d_in[12];
    float* out = (float*)d_out;

    const int B = in_sizes[0] / SEQ;  // 512

    seq2seq_kernel<<<dim3(B / 2), dim3(NTHR), 0, stream>>>(
        inputs, Wih_e, Whh_e, b_e, Wih_d, Whh_d, b_d, We, Wd, Wv, Wf, bfp, out, B);
}

// Round 14
// 600.930 us; speedup vs baseline: 1.0828x; 1.0828x over previous
//
#include <hip/hip_runtime.h>

#define HDIM 128
#define SEQ  14
#define G4   512
#define TLEN 8
#define NTHR 512
#define HPITCH 160   // halves per elem row (320 B): elem0 banks 0-15, elem1 banks 16-31

typedef _Float16 half8 __attribute__((ext_vector_type(8)));
typedef float f32x4 __attribute__((ext_vector_type(4)));
typedef float f32x2 __attribute__((ext_vector_type(2)));

#define LOG2E  1.44269504f
#define LOG2E2 2.88539008f

__device__ __forceinline__ float frcp_(float x) { return __builtin_amdgcn_rcpf(x); }
#if defined(__has_builtin)
#if __has_builtin(__builtin_amdgcn_exp2f)
#define EXP2_(x) __builtin_amdgcn_exp2f(x)
#endif
#endif
#ifndef EXP2_
#define EXP2_(x) __expf((x) * 0.69314718f)
#endif
// inputs pre-scaled by log2e (sig) / 2*log2e (tanh):
__device__ __forceinline__ float fsigP_(float y)  { return frcp_(1.0f + EXP2_(-y)); }
__device__ __forceinline__ float ftanhP_(float y) { return 1.0f - 2.0f * frcp_(EXP2_(y) + 1.0f); }
// unscaled (scores path):
__device__ __forceinline__ float ftanh_(float x)  { return ftanhP_(x * LOG2E2); }

struct __align__(16) SMem {
    __align__(16) float zq[4];             // persistent zero quad (opaque to compiler)
    _Float16 h2[2][2][HPITCH];             // [buf][elem][col], bank-colored
    _Float16 ench[SEQ][2][HPITCH];         // encoder outputs, bank-colored
    _Float16 encWe[SEQ][2][HDIM];          // enc_out @ We
    _Float16 hWdh[2][HDIM];                // h @ Wd
    __align__(16) float ctx2[HDIM + 1][2]; // [s][e]; row 128 = x
    __align__(16) float inp2[SEQ][2];
    float attnw[2][SEQ];
    float asum[2][SEQ];
    float score[2][SEQ];
    float wv[HDIM];
    float wf[HDIM];
};

// One LSTM step for 2 batch elements. A-row r carries elem (r>>2)&1, so for
// writer lanes q<2, D reg0 (= row 4q) is the lane's own element's gate value.
// Activation is SPLIT around the MFMA chains: ig/fg (needing only chains 0,1)
// are computed between chain1 and chain2 issue, so their trans-op stall is
// covered by the other wave's MFMA issue and half the act leaves the tail.
// Weights pre-scaled by log2e (i,f,o) / 2*log2e (g) for bare v_exp_f32.
// Caller must __syncthreads() after.
__device__ __forceinline__ float lstm_core(
    const _Float16* __restrict__ srcBase,  // &h2[buf][0][0]
    _Float16* __restrict__ dstw,           // &h2[nxt][q][16w+l] (q<2)
    f32x2 xv, f32x4 zeroq,
    const half8 (&whh)[4][4], const float (&wih)[4], const float (&bia)[4],
    float& c, int q, int l)
{
    const _Float16* sp = srcBase + ((l >> 2) & 1) * HPITCH + 8 * q;
    half8 a0 = *(const half8*)(sp);
    half8 a1 = *(const half8*)(sp + 32);
    half8 a2 = *(const half8*)(sp + 64);
    half8 a3 = *(const half8*)(sp + 96);
    const float x = (q & 1) ? xv[1] : xv[0];

    // chains for gates i (0) and f (1)
    f32x4 A0 = __builtin_amdgcn_mfma_f32_16x16x32_f16(a0, whh[0][0], zeroq, 0, 0, 0);
    f32x4 A1 = __builtin_amdgcn_mfma_f32_16x16x32_f16(a0, whh[1][0], zeroq, 0, 0, 0);
    A0 = __builtin_amdgcn_mfma_f32_16x16x32_f16(a1, whh[0][1], A0, 0, 0, 0);
    A1 = __builtin_amdgcn_mfma_f32_16x16x32_f16(a1, whh[1][1], A1, 0, 0, 0);
    A0 = __builtin_amdgcn_mfma_f32_16x16x32_f16(a2, whh[0][2], A0, 0, 0, 0);
    A1 = __builtin_amdgcn_mfma_f32_16x16x32_f16(a2, whh[1][2], A1, 0, 0, 0);
    A0 = __builtin_amdgcn_mfma_f32_16x16x32_f16(a3, whh[0][3], A0, 0, 0, 0);
    A1 = __builtin_amdgcn_mfma_f32_16x16x32_f16(a3, whh[1][3], A1, 0, 0, 0);

    // early act: ig/fg — stall covered by the co-resident wave's MFMA issue
    float ig = 0.0f, fg = 0.0f;
    if (q < 2) {
        ig = fsigP_(fmaf(x, wih[0], bia[0]) + A0[0]);
        fg = fsigP_(fmaf(x, wih[1], bia[1]) + A1[0]);
    }

    // chains for gates g (2) and o (3)
    f32x4 A2 = __builtin_amdgcn_mfma_f32_16x16x32_f16(a0, whh[2][0], zeroq, 0, 0, 0);
    f32x4 A3 = __builtin_amdgcn_mfma_f32_16x16x32_f16(a0, whh[3][0], zeroq, 0, 0, 0);
    A2 = __builtin_amdgcn_mfma_f32_16x16x32_f16(a1, whh[2][1], A2, 0, 0, 0);
    A3 = __builtin_amdgcn_mfma_f32_16x16x32_f16(a1, whh[3][1], A3, 0, 0, 0);
    A2 = __builtin_amdgcn_mfma_f32_16x16x32_f16(a2, whh[2][2], A2, 0, 0, 0);
    A3 = __builtin_amdgcn_mfma_f32_16x16x32_f16(a2, whh[3][2], A3, 0, 0, 0);
    A2 = __builtin_amdgcn_mfma_f32_16x16x32_f16(a3, whh[2][3], A2, 0, 0, 0);
    A3 = __builtin_amdgcn_mfma_f32_16x16x32_f16(a3, whh[3][3], A3, 0, 0, 0);

    float hn = 0.0f;
    if (q < 2) {                           // late act tail: gg/og + cell + store
        float gg = ftanhP_(fmaf(x, wih[2], bia[2]) + A2[0]);
        float og = fsigP_(fmaf(x, wih[3], bia[3]) + A3[0]);
        c = fmaf(fg, c, ig * gg);
        hn = og * ftanhP_(c * LOG2E2);
        *dstw = (_Float16)hn;
    }
    return hn;
}

__global__ __launch_bounds__(NTHR, 2) void seq2seq_kernel(
    const float* __restrict__ inputs,
    const float* __restrict__ Wih_e, const float* __restrict__ Whh_e, const float* __restrict__ b_e,
    const float* __restrict__ Wih_d, const float* __restrict__ Whh_d, const float* __restrict__ b_d,
    const float* __restrict__ We, const float* __restrict__ Wd,
    const float* __restrict__ Wv, const float* __restrict__ Wf, const float* __restrict__ bfp,
    float* __restrict__ out, int B)
{
    const int tid  = threadIdx.x;
    const int b0   = blockIdx.x * 2;
    const int w    = tid >> 6;
    const int lane = tid & 63;
    const int q    = lane >> 4;
    const int l    = lane & 15;
    const int wrcol = 16 * w + l;
    __shared__ SMem S;

    const _Float16* s0 = &S.h2[0][0][0];
    const _Float16* s1 = &S.h2[1][0][0];
    _Float16* d0 = &S.h2[0][q & 1][wrcol];
    _Float16* d1 = &S.h2[1][q & 1][wrcol];

    // gate scales: i,f,o -> log2e ; g -> 2*log2e
    const float gscale[4] = {LOG2E, LOG2E, LOG2E2, LOG2E};

    // ---- init ----
    if (tid < 4) S.zq[tid] = 0.0f;
    if (tid < 2 * HDIM) {
        int e = tid >> 7, j = tid & 127;
        S.h2[0][e][j] = (_Float16)0.0f;
        S.h2[1][e][j] = (_Float16)0.0f;
    }
    if (tid < SEQ * 2) {
        int t = tid >> 1, m = tid & 1;
        S.inp2[t][m] = inputs[(b0 + m) * SEQ + t];
        S.asum[m][t] = 0.0f;
    }
    if (tid < HDIM) { S.wv[tid] = Wv[tid]; S.wf[tid] = Wf[tid]; }
    if (tid < 2) S.ctx2[HDIM][tid] = inputs[(b0 + tid) * SEQ + (SEQ - 1)];

    // ---- encoder weights (B-frags, pre-scaled) ----
    half8 whh[4][4];
    float wih[4], bia[4];
    #pragma unroll
    for (int g = 0; g < 4; ++g) {
        int n = g * HDIM + wrcol;
        float sc = gscale[g];
        wih[g] = Wih_e[n] * sc;
        bia[g] = b_e[n] * sc;
        #pragma unroll
        for (int kt = 0; kt < 4; ++kt) {
            half8 f;
            #pragma unroll
            for (int jj = 0; jj < 8; ++jj)
                f[jj] = (_Float16)(Whh_e[(32 * kt + 8 * q + jj) * G4 + n] * sc);
            whh[g][kt] = f;
        }
    }
    float c = 0.0f;
    __syncthreads();

    const f32x4 zeroq = *(const f32x4*)S.zq;   // opaque zeros: 4 persistent VGPRs

    // ---- encoder: 14 steps (7 static-parity pairs), x prefetched across barrier ----
    f32x2 xv = *(const f32x2*)&S.inp2[0][0];
    for (int t = 0; t < SEQ; t += 2) {
        float hn = lstm_core(s0, d1, xv, zeroq, whh, wih, bia, c, q, l);
        if (q < 2) S.ench[t][q][wrcol] = (_Float16)hn;
        xv = *(const f32x2*)&S.inp2[t + 1][0];
        __syncthreads();
        hn = lstm_core(s1, d0, xv, zeroq, whh, wih, bia, c, q, l);
        if (q < 2) S.ench[t + 1][q][wrcol] = (_Float16)hn;
        if (t + 2 < SEQ) xv = *(const f32x2*)&S.inp2[t + 2][0];
        __syncthreads();
    }
    // h now in h2[0]

    // ---- encWe = enc_out @ We (one-time; unscaled weights) ----
    {
        half8 wef[4];
        #pragma unroll
        for (int kt = 0; kt < 4; ++kt) {
            half8 f;
            #pragma unroll
            for (int jj = 0; jj < 8; ++jj)
                f[jj] = (_Float16)We[(32 * kt + 8 * q + jj) * HDIM + wrcol];
            wef[kt] = f;
        }
        for (int t = 0; t < SEQ; ++t) {
            const _Float16* er = &S.ench[t][0][0] + ((l >> 2) & 1) * HPITCH + 8 * q;
            f32x4 dv = zeroq;
            #pragma unroll
            for (int kt = 0; kt < 4; ++kt) {
                half8 a = *(const half8*)(er + 32 * kt);
                dv = __builtin_amdgcn_mfma_f32_16x16x32_f16(a, wef[kt], dv, 0, 0, 0);
            }
            if (q < 2) S.encWe[t][q][wrcol] = (_Float16)dv[0];  // reg0 = row 4q = elem q
        }
    }

    // ---- decoder weights (pre-scaled) ----
    half8 wdf[4];
    #pragma unroll
    for (int g = 0; g < 4; ++g) {
        int n = g * HDIM + wrcol;
        float sc = gscale[g];
        wih[g] = Wih_d[n] * sc;
        bia[g] = b_d[n] * sc;
        #pragma unroll
        for (int kt = 0; kt < 4; ++kt) {
            half8 f;
            #pragma unroll
            for (int jj = 0; jj < 8; ++jj)
                f[jj] = (_Float16)(Whh_d[(32 * kt + 8 * q + jj) * G4 + n] * sc);
            whh[g][kt] = f;
        }
    }
    #pragma unroll
    for (int kt = 0; kt < 4; ++kt) {
        half8 f;
        #pragma unroll
        for (int jj = 0; jj < 8; ++jj)
            f[jj] = (_Float16)Wd[(32 * kt + 8 * q + jj) * HDIM + wrcol];
        wdf[kt] = f;
    }
    float bf0 = bfp[0];
    __syncthreads();   // encWe + x0 visible

    // ---- decoder: 8 steps, parity alternates (h enters in h2[0]) ----
    #pragma unroll 1
    for (int dd = 0; dd < TLEN; ++dd) {
        const bool even = (dd & 1) == 0;
        const _Float16* sC = even ? s0 : s1;
        const _Float16* sO = even ? s1 : s0;
        _Float16* dC = even ? d0 : d1;
        _Float16* dO = even ? d1 : d0;

        // hWd = h @ Wd
        {
            const _Float16* sp = sC + ((l >> 2) & 1) * HPITCH + 8 * q;
            half8 a0 = *(const half8*)(sp);
            half8 a1 = *(const half8*)(sp + 32);
            half8 a2 = *(const half8*)(sp + 64);
            half8 a3 = *(const half8*)(sp + 96);
            f32x4 dv = zeroq;
            dv = __builtin_amdgcn_mfma_f32_16x16x32_f16(a0, wdf[0], dv, 0, 0, 0);
            dv = __builtin_amdgcn_mfma_f32_16x16x32_f16(a1, wdf[1], dv, 0, 0, 0);
            dv = __builtin_amdgcn_mfma_f32_16x16x32_f16(a2, wdf[2], dv, 0, 0, 0);
            dv = __builtin_amdgcn_mfma_f32_16x16x32_f16(a3, wdf[3], dv, 0, 0, 0);
            if (q < 2) S.hWdh[q][wrcol] = (_Float16)dv[0];
        }
        __syncthreads();
        // scores
        if (tid < 2 * SEQ * 16) {
            int p = tid >> 4, sub = tid & 15;
            int m = p & 1, t = p >> 1;
            float s = 0.0f;
            #pragma unroll
            for (int i = 0; i < 8; ++i) {
                int j = sub * 8 + i;
                s = fmaf(ftanh_((float)S.encWe[t][m][j] + (float)S.hWdh[m][j]), S.wv[j], s);
            }
            s += __shfl_down(s, 8, 16);
            s += __shfl_down(s, 4, 16);
            s += __shfl_down(s, 2, 16);
            s += __shfl_down(s, 1, 16);
            if (sub == 0) S.score[m][t] = s;
        }
        __syncthreads();
        // softmax over 14 per element
        if (tid < 2) {
            int m = tid;
            float sc[SEQ]; float mx = -1e30f;
            #pragma unroll
            for (int t = 0; t < SEQ; ++t) { sc[t] = S.score[m][t]; mx = fmaxf(mx, sc[t]); }
            float ssum = 0.0f;
            #pragma unroll
            for (int t = 0; t < SEQ; ++t) { float e = __expf(sc[t] - mx); sc[t] = e; ssum += e; }
            float inv = frcp_(ssum);
            #pragma unroll
            for (int t = 0; t < SEQ; ++t) {
                float a = sc[t] * inv;
                S.attnw[m][t] = a;
                S.asum[m][t] += a;
            }
        }
        __syncthreads();
        // context -> ctx2[j][e]
        if (tid < 256) {
            int e = tid >> 7, j = tid & 127;
            float a = 0.0f;
            #pragma unroll
            for (int t = 0; t < SEQ; ++t)
                a = fmaf(S.attnw[e][t], (float)S.ench[t][e][j], a);
            S.ctx2[j][e] = a;
        }
        __syncthreads();

        // decoder LSTM: 129 steps = 64 static-parity pairs + 1; x prefetched
        const f32x2* xp = (const f32x2*)&S.ctx2[0][0];
        f32x2 xd = xp[0];
        #pragma unroll 1
        for (int s2 = 0; s2 < 64; ++s2) {
            (void)lstm_core(sC, dO, xd, zeroq, whh, wih, bia, c, q, l);
            xd = xp[2 * s2 + 1];           // issued before the barrier
            __syncthreads();
            (void)lstm_core(sO, dC, xd, zeroq, whh, wih, bia, c, q, l);
            xd = xp[2 * s2 + 2];           // s2=63 -> xp[128] = x row, valid
            __syncthreads();
        }
        (void)lstm_core(sC, dO, xd, zeroq, whh, wih, bia, c, q, l);
        __syncthreads();
        // h now in the "other" buffer; output projection -> next x
        const _Float16* hO = even ? &S.h2[1][0][0] : &S.h2[0][0][0];
        if (tid < 32) {
            int m = tid >> 4, part = tid & 15;
            half8 hv = *(const half8*)(hO + m * HPITCH + part * 8);
            float s = 0.0f;
            #pragma unroll
            for (int i = 0; i < 8; ++i) s = fmaf((float)hv[i], S.wf[part * 8 + i], s);
            s += __shfl_down(s, 8, 16);
            s += __shfl_down(s, 4, 16);
            s += __shfl_down(s, 2, 16);
            s += __shfl_down(s, 1, 16);
            if (part == 0) {
                float o = s + bf0;
                out[(b0 + m) * TLEN + dd] = o;
                S.ctx2[HDIM][m] = o;
            }
        }
        __syncthreads();
    }

    // total_attn [B, 14, 1]
    if (tid < 2 * SEQ) {
        int m = tid / SEQ, t = tid % SEQ;
        out[B * TLEN + (b0 + m) * SEQ + t] = S.asum[m][t];
    }
}

extern "C" void kernel_launch(void* const* d_in, const int* in_sizes, int n_in,
                              void* d_out, int out_size, void* d_ws, size_t ws_size,
                              hipStream_t stream) {
    const float* inputs = (const float*)d_in[0];
    const float* Wih_e = (const float*)d_in[2];
    const float* Whh_e = (const float*)d_in[3];
    const float* b_e   = (const float*)d_in[4];
    const float* Wih_d = (const float*)d_in[5];
    const float* Whh_d = (const float*)d_in[6];
    const float* b_d   = (const float*)d_in[7];
    const float* We    = (const float*)d_in[8];
    const float* Wd    = (const float*)d_in[9];
    const float* Wv    = (const float*)d_in[10];
    const float* Wf    = (const float*)d_in[11];
    const float* bfp   = (const float*)d_in[12];
    float* out = (float*)d_out;

    const int B = in_sizes[0] / SEQ;  // 512

    seq2seq_kernel<<<dim3(B / 2), dim3(NTHR), 0, stream>>>(
        inputs, Wih_e, Whh_e, b_e, Wih_d, Whh_d, b_d, We, Wd, Wv, Wf, bfp, out, B);
}

// Round 15
// 507.350 us; speedup vs baseline: 1.2825x; 1.1844x over previous
//
#include <hip/hip_runtime.h>

#define HDIM 128
#define SEQ  14
#define G4   512
#define TLEN 8
#define NTHR 512
#define HPITCH 160   // halves per elem row (320 B): elem0 banks 0-15, elem1 banks 16-31

typedef _Float16 half8 __attribute__((ext_vector_type(8)));
typedef float f32x4 __attribute__((ext_vector_type(4)));
typedef float f32x2 __attribute__((ext_vector_type(2)));

#define LOG2E  1.44269504f
#define LOG2E2 2.88539008f

__device__ __forceinline__ float frcp_(float x) { return __builtin_amdgcn_rcpf(x); }
#if defined(__has_builtin)
#if __has_builtin(__builtin_amdgcn_exp2f)
#define EXP2_(x) __builtin_amdgcn_exp2f(x)
#endif
#endif
#ifndef EXP2_
#define EXP2_(x) __expf((x) * 0.69314718f)
#endif
// inputs pre-scaled by log2e (sig) / 2*log2e (tanh):
__device__ __forceinline__ float fsigP_(float y)  { return frcp_(1.0f + EXP2_(-y)); }
__device__ __forceinline__ float ftanhP_(float y) { return 1.0f - 2.0f * frcp_(EXP2_(y) + 1.0f); }
// unscaled (scores path):
__device__ __forceinline__ float ftanh_(float x)  { return ftanhP_(x * LOG2E2); }

struct __align__(16) SMem {
    __align__(16) float zq[4];             // persistent zero quad (opaque to compiler)
    _Float16 h2[2][2][HPITCH];             // [buf][elem][col], bank-colored
    _Float16 ench[SEQ][2][HPITCH];         // encoder outputs, bank-colored
    _Float16 encWe[SEQ][2][HDIM];          // enc_out @ We
    _Float16 hWdh[2][HDIM];                // h @ Wd
    __align__(16) float ctx2[HDIM + 1][2]; // [s][e]; row 128 = x
    __align__(16) float inp2[SEQ][2];
    float attnw[2][SEQ];
    float asum[2][SEQ];
    float score[2][SEQ];
    float wv[HDIM];
    float wf[HDIM];
};

// One LSTM step for 2 batch elements. A-row r carries elem (r>>2)&1, so for
// writer lanes q<2, D reg0 (= row 4q) is the lane's own element's gate value.
// MFMA chains grouped per gate; compiler interleaves them (R13/R14 showed any
// hand-scheduling here regresses). Weights pre-scaled by log2e (i,f,o) /
// 2*log2e (g) for bare v_exp_f32. Caller must __syncthreads() after.
__device__ __forceinline__ float lstm_core(
    const _Float16* __restrict__ srcBase,  // &h2[buf][0][0]
    _Float16* __restrict__ dstw,           // &h2[nxt][q][16w+l] (q<2)
    f32x2 xv, f32x4 zeroq,
    const half8 (&whh)[4][4], const float (&wih)[4], const float (&bia)[4],
    float& c, int q, int l)
{
    const _Float16* sp = srcBase + ((l >> 2) & 1) * HPITCH + 8 * q;
    half8 a0 = *(const half8*)(sp);
    half8 a1 = *(const half8*)(sp + 32);
    half8 a2 = *(const half8*)(sp + 64);
    half8 a3 = *(const half8*)(sp + 96);
    f32x4 A[4];
    #pragma unroll
    for (int g = 0; g < 4; ++g) {
        A[g] = __builtin_amdgcn_mfma_f32_16x16x32_f16(a0, whh[g][0], zeroq, 0, 0, 0);
        A[g] = __builtin_amdgcn_mfma_f32_16x16x32_f16(a1, whh[g][1], A[g], 0, 0, 0);
        A[g] = __builtin_amdgcn_mfma_f32_16x16x32_f16(a2, whh[g][2], A[g], 0, 0, 0);
        A[g] = __builtin_amdgcn_mfma_f32_16x16x32_f16(a3, whh[g][3], A[g], 0, 0, 0);
    }
    float hn = 0.0f;
    if (q < 2) {                           // writer lanes; reg0 = own element
        float x = (q & 1) ? xv[1] : xv[0];
        float ig = fsigP_(fmaf(x, wih[0], bia[0]) + A[0][0]);
        float fg = fsigP_(fmaf(x, wih[1], bia[1]) + A[1][0]);
        float gg = ftanhP_(fmaf(x, wih[2], bia[2]) + A[2][0]);
        float og = fsigP_(fmaf(x, wih[3], bia[3]) + A[3][0]);
        c = fmaf(fg, c, ig * gg);
        hn = og * ftanhP_(c * LOG2E2);
        *dstw = (_Float16)hn;
    }
    return hn;
}

__global__ __launch_bounds__(NTHR, 2) void seq2seq_kernel(
    const float* __restrict__ inputs,
    const float* __restrict__ Wih_e, const float* __restrict__ Whh_e, const float* __restrict__ b_e,
    const float* __restrict__ Wih_d, const float* __restrict__ Whh_d, const float* __restrict__ b_d,
    const float* __restrict__ We, const float* __restrict__ Wd,
    const float* __restrict__ Wv, const float* __restrict__ Wf, const float* __restrict__ bfp,
    float* __restrict__ out, int B)
{
    const int tid  = threadIdx.x;
    const int b0   = blockIdx.x * 2;
    const int w    = tid >> 6;
    const int lane = tid & 63;
    const int q    = lane >> 4;
    const int l    = lane & 15;
    const int wrcol = 16 * w + l;
    __shared__ SMem S;

    const _Float16* s0 = &S.h2[0][0][0];
    const _Float16* s1 = &S.h2[1][0][0];
    _Float16* d0 = &S.h2[0][q & 1][wrcol];
    _Float16* d1 = &S.h2[1][q & 1][wrcol];

    // gate scales: i,f,o -> log2e ; g -> 2*log2e
    const float gscale[4] = {LOG2E, LOG2E, LOG2E2, LOG2E};

    // ---- init ----
    if (tid < 4) S.zq[tid] = 0.0f;
    if (tid < 2 * HDIM) {
        int e = tid >> 7, j = tid & 127;
        S.h2[0][e][j] = (_Float16)0.0f;
        S.h2[1][e][j] = (_Float16)0.0f;
    }
    if (tid < SEQ * 2) {
        int t = tid >> 1, m = tid & 1;
        S.inp2[t][m] = inputs[(b0 + m) * SEQ + t];
        S.asum[m][t] = 0.0f;
    }
    if (tid < HDIM) { S.wv[tid] = Wv[tid]; S.wf[tid] = Wf[tid]; }
    if (tid < 2) S.ctx2[HDIM][tid] = inputs[(b0 + tid) * SEQ + (SEQ - 1)];

    // ---- encoder weights (B-frags, pre-scaled) ----
    half8 whh[4][4];
    float wih[4], bia[4];
    #pragma unroll
    for (int g = 0; g < 4; ++g) {
        int n = g * HDIM + wrcol;
        float sc = gscale[g];
        wih[g] = Wih_e[n] * sc;
        bia[g] = b_e[n] * sc;
        #pragma unroll
        for (int kt = 0; kt < 4; ++kt) {
            half8 f;
            #pragma unroll
            for (int jj = 0; jj < 8; ++jj)
                f[jj] = (_Float16)(Whh_e[(32 * kt + 8 * q + jj) * G4 + n] * sc);
            whh[g][kt] = f;
        }
    }
    float c = 0.0f;
    __syncthreads();

    const f32x4 zeroq = *(const f32x4*)S.zq;   // opaque zeros: 4 persistent VGPRs

    // ---- encoder: 14 steps (7 static-parity pairs), x prefetched across barrier ----
    f32x2 xv = *(const f32x2*)&S.inp2[0][0];
    for (int t = 0; t < SEQ; t += 2) {
        float hn = lstm_core(s0, d1, xv, zeroq, whh, wih, bia, c, q, l);
        if (q < 2) S.ench[t][q][wrcol] = (_Float16)hn;
        xv = *(const f32x2*)&S.inp2[t + 1][0];
        __syncthreads();
        hn = lstm_core(s1, d0, xv, zeroq, whh, wih, bia, c, q, l);
        if (q < 2) S.ench[t + 1][q][wrcol] = (_Float16)hn;
        if (t + 2 < SEQ) xv = *(const f32x2*)&S.inp2[t + 2][0];
        __syncthreads();
    }
    // h now in h2[0]

    // ---- encWe = enc_out @ We (one-time; unscaled weights) ----
    {
        half8 wef[4];
        #pragma unroll
        for (int kt = 0; kt < 4; ++kt) {
            half8 f;
            #pragma unroll
            for (int jj = 0; jj < 8; ++jj)
                f[jj] = (_Float16)We[(32 * kt + 8 * q + jj) * HDIM + wrcol];
            wef[kt] = f;
        }
        for (int t = 0; t < SEQ; ++t) {
            const _Float16* er = &S.ench[t][0][0] + ((l >> 2) & 1) * HPITCH + 8 * q;
            f32x4 dv = zeroq;
            #pragma unroll
            for (int kt = 0; kt < 4; ++kt) {
                half8 a = *(const half8*)(er + 32 * kt);
                dv = __builtin_amdgcn_mfma_f32_16x16x32_f16(a, wef[kt], dv, 0, 0, 0);
            }
            if (q < 2) S.encWe[t][q][wrcol] = (_Float16)dv[0];  // reg0 = row 4q = elem q
        }
    }

    // ---- decoder weights (pre-scaled) ----
    half8 wdf[4];
    #pragma unroll
    for (int g = 0; g < 4; ++g) {
        int n = g * HDIM + wrcol;
        float sc = gscale[g];
        wih[g] = Wih_d[n] * sc;
        bia[g] = b_d[n] * sc;
        #pragma unroll
        for (int kt = 0; kt < 4; ++kt) {
            half8 f;
            #pragma unroll
            for (int jj = 0; jj < 8; ++jj)
                f[jj] = (_Float16)(Whh_d[(32 * kt + 8 * q + jj) * G4 + n] * sc);
            whh[g][kt] = f;
        }
    }
    #pragma unroll
    for (int kt = 0; kt < 4; ++kt) {
        half8 f;
        #pragma unroll
        for (int jj = 0; jj < 8; ++jj)
            f[jj] = (_Float16)Wd[(32 * kt + 8 * q + jj) * HDIM + wrcol];
        wdf[kt] = f;
    }
    float bf0 = bfp[0];
    __syncthreads();   // encWe + x0 visible

    // ---- decoder: 8 steps, parity alternates (h enters in h2[0]) ----
    #pragma unroll 1
    for (int dd = 0; dd < TLEN; ++dd) {
        const bool even = (dd & 1) == 0;
        const _Float16* sC = even ? s0 : s1;
        const _Float16* sO = even ? s1 : s0;
        _Float16* dC = even ? d0 : d1;
        _Float16* dO = even ? d1 : d0;

        // hWd = h @ Wd
        {
            const _Float16* sp = sC + ((l >> 2) & 1) * HPITCH + 8 * q;
            half8 a0 = *(const half8*)(sp);
            half8 a1 = *(const half8*)(sp + 32);
            half8 a2 = *(const half8*)(sp + 64);
            half8 a3 = *(const half8*)(sp + 96);
            f32x4 dv = zeroq;
            dv = __builtin_amdgcn_mfma_f32_16x16x32_f16(a0, wdf[0], dv, 0, 0, 0);
            dv = __builtin_amdgcn_mfma_f32_16x16x32_f16(a1, wdf[1], dv, 0, 0, 0);
            dv = __builtin_amdgcn_mfma_f32_16x16x32_f16(a2, wdf[2], dv, 0, 0, 0);
            dv = __builtin_amdgcn_mfma_f32_16x16x32_f16(a3, wdf[3], dv, 0, 0, 0);
            if (q < 2) S.hWdh[q][wrcol] = (_Float16)dv[0];
        }
        __syncthreads();
        // scores
        if (tid < 2 * SEQ * 16) {
            int p = tid >> 4, sub = tid & 15;
            int m = p & 1, t = p >> 1;
            float s = 0.0f;
            #pragma unroll
            for (int i = 0; i < 8; ++i) {
                int j = sub * 8 + i;
                s = fmaf(ftanh_((float)S.encWe[t][m][j] + (float)S.hWdh[m][j]), S.wv[j], s);
            }
            s += __shfl_down(s, 8, 16);
            s += __shfl_down(s, 4, 16);
            s += __shfl_down(s, 2, 16);
            s += __shfl_down(s, 1, 16);
            if (sub == 0) S.score[m][t] = s;
        }
        __syncthreads();
        // softmax over 14 per element
        if (tid < 2) {
            int m = tid;
            float sc[SEQ]; float mx = -1e30f;
            #pragma unroll
            for (int t = 0; t < SEQ; ++t) { sc[t] = S.score[m][t]; mx = fmaxf(mx, sc[t]); }
            float ssum = 0.0f;
            #pragma unroll
            for (int t = 0; t < SEQ; ++t) { float e = __expf(sc[t] - mx); sc[t] = e; ssum += e; }
            float inv = frcp_(ssum);
            #pragma unroll
            for (int t = 0; t < SEQ; ++t) {
                float a = sc[t] * inv;
                S.attnw[m][t] = a;
                S.asum[m][t] += a;
            }
        }
        __syncthreads();
        // context -> ctx2[j][e]
        if (tid < 256) {
            int e = tid >> 7, j = tid & 127;
            float a = 0.0f;
            #pragma unroll
            for (int t = 0; t < SEQ; ++t)
                a = fmaf(S.attnw[e][t], (float)S.ench[t][e][j], a);
            S.ctx2[j][e] = a;
        }
        __syncthreads();

        // decoder LSTM: 129 steps = 64 static-parity pairs + 1; x prefetched
        const f32x2* xp = (const f32x2*)&S.ctx2[0][0];
        f32x2 xd = xp[0];
        #pragma unroll 1
        for (int s2 = 0; s2 < 64; ++s2) {
            (void)lstm_core(sC, dO, xd, zeroq, whh, wih, bia, c, q, l);
            xd = xp[2 * s2 + 1];           // issued before the barrier
            __syncthreads();
            (void)lstm_core(sO, dC, xd, zeroq, whh, wih, bia, c, q, l);
            xd = xp[2 * s2 + 2];           // s2=63 -> xp[128] = x row, valid
            __syncthreads();
        }
        (void)lstm_core(sC, dO, xd, zeroq, whh, wih, bia, c, q, l);
        __syncthreads();
        // h now in the "other" buffer; output projection -> next x
        const _Float16* hO = even ? &S.h2[1][0][0] : &S.h2[0][0][0];
        if (tid < 32) {
            int m = tid >> 4, part = tid & 15;
            half8 hv = *(const half8*)(hO + m * HPITCH + part * 8);
            float s = 0.0f;
            #pragma unroll
            for (int i = 0; i < 8; ++i) s = fmaf((float)hv[i], S.wf[part * 8 + i], s);
            s += __shfl_down(s, 8, 16);
            s += __shfl_down(s, 4, 16);
            s += __shfl_down(s, 2, 16);
            s += __shfl_down(s, 1, 16);
            if (part == 0) {
                float o = s + bf0;
                out[(b0 + m) * TLEN + dd] = o;
                S.ctx2[HDIM][m] = o;
            }
        }
        __syncthreads();
    }

    // total_attn [B, 14, 1]
    if (tid < 2 * SEQ) {
        int m = tid / SEQ, t = tid % SEQ;
        out[B * TLEN + (b0 + m) * SEQ + t] = S.asum[m][t];
    }
}

extern "C" void kernel_launch(void* const* d_in, const int* in_sizes, int n_in,
                              void* d_out, int out_size, void* d_ws, size_t ws_size,
                              hipStream_t stream) {
    const float* inputs = (const float*)d_in[0];
    const float* Wih_e = (const float*)d_in[2];
    const float* Whh_e = (const float*)d_in[3];
    const float* b_e   = (const float*)d_in[4];
    const float* Wih_d = (const float*)d_in[5];
    const float* Whh_d = (const float*)d_in[6];
    const float* b_d   = (const float*)d_in[7];
    const float* We    = (const float*)d_in[8];
    const float* Wd    = (const float*)d_in[9];
    const float* Wv    = (const float*)d_in[10];
    const float* Wf    = (const float*)d_in[11];
    const float* bfp   = (const float*)d_in[12];
    float* out = (float*)d_out;

    const int B = in_sizes[0] / SEQ;  // 512

    seq2seq_kernel<<<dim3(B / 2), dim3(NTHR), 0, stream>>>(
        inputs, Wih_e, Whh_e, b_e, Wih_d, Whh_d, b_d, We, Wd, Wv, Wf, bfp, out, B);
}